// Round 4
// baseline (321.206 us; speedup 1.0000x reference)
//
#include <hip/hip_runtime.h>
#include <hip/hip_bf16.h>

constexpr int B = 4, N = 8192, S = 2048;
constexpr int XS = 260;   // LDS X-tile row stride (elements); 260 => conflict-light b64s

typedef __attribute__((ext_vector_type(8))) short short8;
typedef __attribute__((ext_vector_type(4))) float v4f;

__device__ inline float u2f(ushort u) {
    union { ushort u; __hip_bfloat16 h; } c; c.u = u; return __bfloat162float(c.h);
}
__device__ inline ushort f2u(float f) {
    union { ushort u; __hip_bfloat16 h; } c; c.h = __float2bfloat16(f); return c.u;
}

// ------------------------------------------------- prep: cast W + zero ----
__global__ __launch_bounds__(256) void prep_kernel(
    const float* __restrict__ W1, const float* __restrict__ W2,
    __hip_bfloat16* __restrict__ W1c, __hip_bfloat16* __restrict__ W2c,
    float* __restrict__ zero_region)
{
    int i = blockIdx.x * 256 + threadIdx.x;
    if (i < 98304) W1c[i] = __float2bfloat16(W1[i]);
    else if (i < 98304 + 65536) W2c[i - 98304] = __float2bfloat16(W2[i - 98304]);
    else if (i < 98304 + 65536 + 2112) zero_region[i - 98304 - 65536] = 0.f;
}

// ---------------------------------------------------------------- 3-NN ----
// 16 lanes per query; 2048 blocks (5/CU, LDS-capped)
__global__ __launch_bounds__(256) void knn_kernel(
    const float* __restrict__ pos1, const float* __restrict__ pos2,
    float* __restrict__ wgt, int* __restrict__ idxb)
{
    __shared__ float4 p2s[S];
    const int b = blockIdx.y;
    for (int s = threadIdx.x; s < S; s += 256) {
        float x = pos2[(b * 3 + 0) * S + s];
        float y = pos2[(b * 3 + 1) * S + s];
        float z = pos2[(b * 3 + 2) * S + s];
        p2s[s] = make_float4(x, y, z, x * x + y * y + z * z);
    }
    __syncthreads();

    const int qi = blockIdx.x * 16 + (threadIdx.x >> 4);
    const int lp = threadIdx.x & 15;
    const float x1 = pos1[(b * 3 + 0) * N + qi];
    const float y1 = pos1[(b * 3 + 1) * N + qi];
    const float z1 = pos1[(b * 3 + 2) * N + qi];
    const float t1 = x1 * x1 + y1 * y1 + z1 * z1;

    float d0 = 3.4e38f, d1 = 3.4e38f, d2 = 3.4e38f;
    int i0 = 0x7fffffff, i1 = 0x7fffffff, i2 = 0x7fffffff;

    for (int t = 0; t < S / 16; ++t) {
        int s = 16 * t + lp;
        float4 p = p2s[s];
        float dot = x1 * p.x + y1 * p.y + z1 * p.z;
        float dd = (t1 - 2.0f * dot) + p.w;
        if (dd < d2) {
            if (dd < d0)      { d2 = d1; i2 = i1; d1 = d0; i1 = i0; d0 = dd; i0 = s; }
            else if (dd < d1) { d2 = d1; i2 = i1; d1 = dd; i1 = s; }
            else              { d2 = dd; i2 = s; }
        }
    }

    // merge top-3 across the 16 lanes of the query group; (d, idx) lexicographic
    #pragma unroll
    for (int m = 1; m <= 8; m <<= 1) {
        float c0 = __shfl_xor(d0, m), c1 = __shfl_xor(d1, m), c2 = __shfl_xor(d2, m);
        int   j0 = __shfl_xor(i0, m), j1 = __shfl_xor(i1, m), j2 = __shfl_xor(i2, m);
        float cd[3] = {c0, c1, c2};
        int   cj[3] = {j0, j1, j2};
        #pragma unroll
        for (int k = 0; k < 3; ++k) {
            float d = cd[k]; int id = cj[k];
            bool l0 = (d < d0) || (d == d0 && id < i0);
            bool l1 = (d < d1) || (d == d1 && id < i1);
            bool l2 = (d < d2) || (d == d2 && id < i2);
            if (l0)      { d2 = d1; i2 = i1; d1 = d0; i1 = i0; d0 = d; i0 = id; }
            else if (l1) { d2 = d1; i2 = i1; d1 = d; i1 = id; }
            else if (l2) { d2 = d; i2 = id; }
        }
    }

    if (lp == 0) {
        float w0 = 1.f / fmaxf(d0, 1e-10f);
        float w1 = 1.f / fmaxf(d1, 1e-10f);
        float w2 = 1.f / fmaxf(d2, 1e-10f);
        float inv = 1.f / (w0 + w1 + w2);
        i0 = ((unsigned)i0 < S) ? i0 : 0;
        i1 = ((unsigned)i1 < S) ? i1 : 0;
        i2 = ((unsigned)i2 < S) ? i2 : 0;
        int base = (b * N + qi) * 3;
        wgt[base + 0] = w0 * inv; wgt[base + 1] = w1 * inv; wgt[base + 2] = w2 * inv;
        idxb[base + 0] = i0; idxb[base + 1] = i1; idxb[base + 2] = i2;
    }
}

// --------------------------------------------------------- transpose -----
__global__ void transpose_k(const float* __restrict__ in,
                            __hip_bfloat16* __restrict__ out,
                            int L, int in_bstride, int out_stride, int out_bstride,
                            int col_off)
{
    __shared__ __hip_bfloat16 t[32][33];
    const int b = blockIdx.z;
    const int l0 = blockIdx.x * 32, c0 = blockIdx.y * 32;
    const int tx = threadIdx.x, ty = threadIdx.y;
    const float* ip = in + (size_t)b * in_bstride;
    #pragma unroll
    for (int i = 0; i < 4; ++i)
        t[ty + 8 * i][tx] = __float2bfloat16(ip[(size_t)(c0 + ty + 8 * i) * L + l0 + tx]);
    __syncthreads();
    __hip_bfloat16* op = out + (size_t)b * out_bstride + col_off;
    #pragma unroll
    for (int i = 0; i < 4; ++i)
        op[(size_t)(l0 + ty + 8 * i) * out_stride + c0 + tx] = t[tx][ty + 8 * i];
}

// ------------------------------------------------ GEMM1 (fused interp) ----
// Block: 128 threads = 2 waves; 64 rows/block, 32 rows/wave (nf=2).
// X tile: cols 0..255 = interp(f2T, idx, wgt) staged in LDS; cols 256..383
// read directly from f1T (row-contiguous bf16). Writes y[B,N,256] bf16.
__global__ __launch_bounds__(128) void gemm1_kernel(
    const __hip_bfloat16* __restrict__ W, const float* __restrict__ bias,
    const __hip_bfloat16* __restrict__ f2T, const __hip_bfloat16* __restrict__ f1T,
    const int* __restrict__ idxb, const float* __restrict__ wgt,
    __hip_bfloat16* __restrict__ y)
{
    __shared__ __align__(16) __hip_bfloat16 Xs[64 * XS];
    const int t = threadIdx.x;
    const int b = blockIdx.y;
    const int n0 = blockIdx.x * 64;

    // ---- stage interpolated features (rows n0..n0+63, cols 0..255) ----
    {
        const int lp = t & 63, half = t >> 6;
        for (int it = 0; it < 32; ++it) {
            int r = it * 2 + half;
            int base = (b * N + n0 + r) * 3;
            int s0 = idxb[base], s1 = idxb[base + 1], s2 = idxb[base + 2];
            s0 = ((unsigned)s0 < S) ? s0 : 0;
            s1 = ((unsigned)s1 < S) ? s1 : 0;
            s2 = ((unsigned)s2 < S) ? s2 : 0;
            float w0 = wgt[base], w1 = wgt[base + 1], w2 = wgt[base + 2];
            const ushort4 a = *(const ushort4*)(f2T + ((size_t)b * S + s0) * 256 + lp * 4);
            const ushort4 c = *(const ushort4*)(f2T + ((size_t)b * S + s1) * 256 + lp * 4);
            const ushort4 d = *(const ushort4*)(f2T + ((size_t)b * S + s2) * 256 + lp * 4);
            ushort4 o;
            o.x = f2u(w0 * u2f(a.x) + w1 * u2f(c.x) + w2 * u2f(d.x));
            o.y = f2u(w0 * u2f(a.y) + w1 * u2f(c.y) + w2 * u2f(d.y));
            o.z = f2u(w0 * u2f(a.z) + w1 * u2f(c.z) + w2 * u2f(d.z));
            o.w = f2u(w0 * u2f(a.w) + w1 * u2f(c.w) + w2 * u2f(d.w));
            *(ushort4*)(Xs + r * XS + lp * 4) = o;
        }
    }
    __syncthreads();

    const int w = t >> 6, lane = t & 63;
    const int q = lane >> 4, r = lane & 15;

    v4f acc[16][2];
    #pragma unroll
    for (int mt = 0; mt < 16; ++mt) {
        acc[mt][0] = (v4f){0.f, 0.f, 0.f, 0.f};
        acc[mt][1] = (v4f){0.f, 0.f, 0.f, 0.f};
    }

    const short* f1r0 = (const short*)f1T + ((size_t)b * N + n0 + w * 32 + r) * 128;
    const short* f1r1 = f1r0 + 16 * 128;
    const char* XsB = (const char*)Xs;

    #pragma unroll
    for (int kk = 0; kk < 12; ++kk) {
        short8 bf0, bf1;
        if (kk < 8) {
            const uint2* p0 = (const uint2*)(XsB + (w * 32 + r) * (XS * 2) + kk * 64 + q * 16);
            const uint2* p1 = (const uint2*)(XsB + (w * 32 + 16 + r) * (XS * 2) + kk * 64 + q * 16);
            union { uint2 d[2]; short8 s; } u0, u1;
            u0.d[0] = p0[0]; u0.d[1] = p0[1];
            u1.d[0] = p1[0]; u1.d[1] = p1[1];
            bf0 = u0.s; bf1 = u1.s;
        } else {
            int k1 = (kk - 8) * 32 + q * 8;
            bf0 = *(const short8*)(f1r0 + k1);
            bf1 = *(const short8*)(f1r1 + k1);
        }
        #pragma unroll
        for (int mt = 0; mt < 16; ++mt) {
            short8 af = *(const short8*)((const short*)W + (size_t)(mt * 16 + r) * 384 + kk * 32 + q * 8);
            acc[mt][0] = __builtin_amdgcn_mfma_f32_16x16x32_bf16(af, bf0, acc[mt][0], 0, 0, 0);
            acc[mt][1] = __builtin_amdgcn_mfma_f32_16x16x32_bf16(af, bf1, acc[mt][1], 0, 0, 0);
        }
    }

    #pragma unroll
    for (int nf = 0; nf < 2; ++nf) {
        __hip_bfloat16* yr = y + ((size_t)b * N + n0 + w * 32 + nf * 16 + r) * 256;
        #pragma unroll
        for (int mt = 0; mt < 16; ++mt) {
            int o = mt * 16 + q * 4;
            float4 bi = *(const float4*)(bias + o);
            ushort4 pk;
            pk.x = f2u(acc[mt][nf][0] + bi.x);
            pk.y = f2u(acc[mt][nf][1] + bi.y);
            pk.z = f2u(acc[mt][nf][2] + bi.z);
            pk.w = f2u(acc[mt][nf][3] + bi.w);
            *(ushort4*)(yr + o) = pk;
        }
    }
}

// ------------------------------------- GEMM2 (fused BN1+ReLU, in-place) ---
__device__ inline short8 bnrelu(short8 xv, const float* __restrict__ ss, int k) {
    union { short8 s; ushort u[8]; } in, out;
    in.s = xv;
    #pragma unroll
    for (int j = 0; j < 8; ++j)
        out.u[j] = f2u(fmaxf(u2f(in.u[j]) * ss[k + j] + ss[256 + k + j], 0.f));
    return out.s;
}

__global__ __launch_bounds__(128) void gemm2_kernel(
    const __hip_bfloat16* __restrict__ W, const float* __restrict__ bias,
    const float* __restrict__ ss, __hip_bfloat16* __restrict__ y)
{
    const int t = threadIdx.x, w = t >> 6, lane = t & 63;
    const int q = lane >> 4, r = lane & 15;
    const int b = blockIdx.y;
    const int n0 = blockIdx.x * 64;

    const short* y0 = (const short*)y + ((size_t)b * N + n0 + w * 32 + r) * 256;
    const short* y1 = y0 + 16 * 256;

    v4f acc[16][2];
    #pragma unroll
    for (int mt = 0; mt < 16; ++mt) {
        acc[mt][0] = (v4f){0.f, 0.f, 0.f, 0.f};
        acc[mt][1] = (v4f){0.f, 0.f, 0.f, 0.f};
    }

    #pragma unroll
    for (int kk = 0; kk < 8; ++kk) {
        int k = kk * 32 + q * 8;
        short8 bf0 = bnrelu(*(const short8*)(y0 + k), ss, k);
        short8 bf1 = bnrelu(*(const short8*)(y1 + k), ss, k);
        #pragma unroll
        for (int mt = 0; mt < 16; ++mt) {
            short8 af = *(const short8*)((const short*)W + (size_t)(mt * 16 + r) * 256 + k);
            acc[mt][0] = __builtin_amdgcn_mfma_f32_16x16x32_bf16(af, bf0, acc[mt][0], 0, 0, 0);
            acc[mt][1] = __builtin_amdgcn_mfma_f32_16x16x32_bf16(af, bf1, acc[mt][1], 0, 0, 0);
        }
    }

    #pragma unroll
    for (int nf = 0; nf < 2; ++nf) {
        __hip_bfloat16* yr = y + ((size_t)b * N + n0 + w * 32 + nf * 16 + r) * 256;
        #pragma unroll
        for (int mt = 0; mt < 16; ++mt) {
            int o = mt * 16 + q * 4;
            float4 bi = *(const float4*)(bias + o);
            ushort4 pk;
            pk.x = f2u(acc[mt][nf][0] + bi.x);
            pk.y = f2u(acc[mt][nf][1] + bi.y);
            pk.z = f2u(acc[mt][nf][2] + bi.z);
            pk.w = f2u(acc[mt][nf][3] + bi.w);
            *(ushort4*)(yr + o) = pk;
        }
    }
}

// --------------------------- BN stats + last-block finalize (scale/shift) --
__global__ __launch_bounds__(256) void stats_kernel(
    const __hip_bfloat16* __restrict__ Y, float* __restrict__ sums,
    const float* __restrict__ g, const float* __restrict__ be,
    float* __restrict__ ss, unsigned* __restrict__ ctr)
{
    const int o = threadIdx.x;
    const size_t r0 = (size_t)blockIdx.x * 64;
    const ushort* Yp = (const ushort*)Y;
    float s = 0.f, s2 = 0.f;
    for (int i = 0; i < 64; ++i) {
        float v = u2f(Yp[(r0 + i) * 256 + o]);
        s += v; s2 += v * v;
    }
    atomicAdd(&sums[o], s);
    atomicAdd(&sums[256 + o], s2);
    __threadfence();
    __syncthreads();
    __shared__ int lastf;
    if (o == 0) lastf = (atomicAdd(ctr, 1u) == gridDim.x - 1) ? 1 : 0;
    __syncthreads();
    if (lastf) {
        float sv  = __hip_atomic_load(&sums[o],       __ATOMIC_RELAXED, __HIP_MEMORY_SCOPE_AGENT);
        float s2v = __hip_atomic_load(&sums[256 + o], __ATOMIC_RELAXED, __HIP_MEMORY_SCOPE_AGENT);
        float mean = sv * (1.f / 32768.f);
        float var = s2v * (1.f / 32768.f) - mean * mean;
        float rstd = rsqrtf(var + 1e-5f);
        float sc = g[o] * rstd;
        ss[o] = sc;
        ss[256 + o] = be[o] - mean * sc;
    }
}

// ------------------ final BN+ReLU + transpose to [B,256,N] fp32 out ------
__global__ void final_kernel(const __hip_bfloat16* __restrict__ Y,
                             const float* __restrict__ ss,
                             float* __restrict__ out)
{
    __shared__ float tl[32][33];
    const int b = blockIdx.z;
    const int n0 = blockIdx.x * 32, o0 = blockIdx.y * 32;
    const int tx = threadIdx.x, ty = threadIdx.y;
    const float sc = ss[o0 + tx], sh = ss[256 + o0 + tx];
    const ushort* Yp = (const ushort*)Y;
    #pragma unroll
    for (int i = 0; i < 4; ++i) {
        float v = u2f(Yp[((size_t)b * N + n0 + ty + 8 * i) * 256 + o0 + tx]);
        tl[ty + 8 * i][tx] = fmaxf(v * sc + sh, 0.f);
    }
    __syncthreads();
    #pragma unroll
    for (int i = 0; i < 4; ++i)
        out[((size_t)b * 256 + o0 + ty + 8 * i) * N + n0 + tx] = tl[tx][ty + 8 * i];
}

// ------------------------------------------------------------ launch -----
extern "C" void kernel_launch(void* const* d_in, const int* in_sizes, int n_in,
                              void* d_out, int out_size, void* d_ws, size_t ws_size,
                              hipStream_t stream)
{
    (void)in_sizes; (void)n_in; (void)out_size;
    // ws layout (30 MB):
    //  [0,384K) idxb | [384K,768K) wgt | [768K..794632) sums1/sums2/ss1/ss2/ctrs
    //  [800K..992K) W1c | [992K..1.09M) W2c | [2M,6M) f2T | [6M,14M) f1T | [14M,30M) y
    if (ws_size < (30u << 20)) return;

    const float* pos1 = (const float*)d_in[0];
    const float* pos2 = (const float*)d_in[1];
    const float* f1   = (const float*)d_in[2];
    const float* f2   = (const float*)d_in[3];
    const float* W1   = (const float*)d_in[4];
    const float* b1   = (const float*)d_in[5];
    const float* g1   = (const float*)d_in[6];
    const float* be1  = (const float*)d_in[7];
    const float* W2   = (const float*)d_in[8];
    const float* b2   = (const float*)d_in[9];
    const float* g2   = (const float*)d_in[10];
    const float* be2  = (const float*)d_in[11];

    char* ws = (char*)d_ws;
    int*      idxb  = (int*)(ws + 0);
    float*    wgt   = (float*)(ws + 393216);
    float*    sums1 = (float*)(ws + 786432);
    float*    sums2 = sums1 + 512;
    float*    ss1   = sums2 + 512;
    float*    ss2   = ss1 + 512;
    unsigned* ctr1  = (unsigned*)(ss2 + 512);
    unsigned* ctr2  = ctr1 + 1;
    __hip_bfloat16* W1c = (__hip_bfloat16*)(ws + 819200);
    __hip_bfloat16* W2c = (__hip_bfloat16*)(ws + 1015808);
    __hip_bfloat16* f2T = (__hip_bfloat16*)(ws + (2u << 20));
    __hip_bfloat16* f1T = (__hip_bfloat16*)(ws + (6u << 20));
    __hip_bfloat16* y   = (__hip_bfloat16*)(ws + (14u << 20));

    prep_kernel<<<649, 256, 0, stream>>>(W1, W2, W1c, W2c, sums1);

    knn_kernel<<<dim3(N / 16, B), 256, 0, stream>>>(pos1, pos2, wgt, idxb);

    // feature2 [B,256,S] -> f2T [B,S,256]
    transpose_k<<<dim3(S / 32, 256 / 32, B), dim3(32, 8), 0, stream>>>(
        f2, f2T, S, 256 * S, 256, S * 256, 0);
    // feature1 [B,128,N] -> f1T [B,N,128]
    transpose_k<<<dim3(N / 32, 128 / 32, B), dim3(32, 8), 0, stream>>>(
        f1, f1T, N, 128 * N, 128, N * 128, 0);

    gemm1_kernel<<<dim3(N / 64, B), 128, 0, stream>>>(W1c, b1, f2T, f1T, idxb, wgt, y);
    stats_kernel<<<512, 256, 0, stream>>>(y, sums1, g1, be1, ss1, ctr1);
    gemm2_kernel<<<dim3(N / 64, B), 128, 0, stream>>>(W2c, b2, ss1, y);
    stats_kernel<<<512, 256, 0, stream>>>(y, sums2, g2, be2, ss2, ctr2);
    final_kernel<<<dim3(N / 32, 256 / 32, B), dim3(32, 8), 0, stream>>>(
        y, ss2, (float*)d_out);
}

// Round 5
// 290.492 us; speedup vs baseline: 1.1057x; 1.1057x over previous
//
#include <hip/hip_runtime.h>
#include <hip/hip_bf16.h>

constexpr int B = 4, N = 8192, S = 2048;

typedef __attribute__((ext_vector_type(8))) short short8;
typedef __attribute__((ext_vector_type(4))) float v4f;

__device__ inline float u2f(ushort u) {
    union { ushort u; __hip_bfloat16 h; } c; c.u = u; return __bfloat162float(c.h);
}
__device__ inline ushort f2u(float f) {
    union { ushort u; __hip_bfloat16 h; } c; c.h = __float2bfloat16(f); return c.u;
}

// ------------------------------------------------- prep: cast W + zero ----
__global__ __launch_bounds__(256) void prep_kernel(
    const float* __restrict__ W1, const float* __restrict__ W2,
    __hip_bfloat16* __restrict__ W1c, __hip_bfloat16* __restrict__ W2c,
    float* __restrict__ zero_region)
{
    int i = blockIdx.x * 256 + threadIdx.x;
    if (i < 98304) W1c[i] = __float2bfloat16(W1[i]);
    else if (i < 163840) W2c[i - 98304] = __float2bfloat16(W2[i - 98304]);
    else if (i < 164864) zero_region[i - 163840] = 0.f;
}

// ---------------------------------------------------------------- 3-NN ----
__global__ __launch_bounds__(256) void knn_kernel(
    const float* __restrict__ pos1, const float* __restrict__ pos2,
    float* __restrict__ wgt, int* __restrict__ idxb)
{
    __shared__ float4 p2s[S];
    const int b = blockIdx.y;
    for (int s = threadIdx.x; s < S; s += 256) {
        float x = pos2[(b * 3 + 0) * S + s];
        float y = pos2[(b * 3 + 1) * S + s];
        float z = pos2[(b * 3 + 2) * S + s];
        p2s[s] = make_float4(x, y, z, x * x + y * y + z * z);
    }
    __syncthreads();

    const int qi = blockIdx.x * 16 + (threadIdx.x >> 4);
    const int lp = threadIdx.x & 15;
    const float x1 = pos1[(b * 3 + 0) * N + qi];
    const float y1 = pos1[(b * 3 + 1) * N + qi];
    const float z1 = pos1[(b * 3 + 2) * N + qi];
    const float t1 = x1 * x1 + y1 * y1 + z1 * z1;

    float d0 = 3.4e38f, d1 = 3.4e38f, d2 = 3.4e38f;
    int i0 = 0x7fffffff, i1 = 0x7fffffff, i2 = 0x7fffffff;

    for (int t = 0; t < S / 16; ++t) {
        int s = 16 * t + lp;
        float4 p = p2s[s];
        float dot = x1 * p.x + y1 * p.y + z1 * p.z;
        float dd = (t1 - 2.0f * dot) + p.w;
        if (dd < d2) {
            if (dd < d0)      { d2 = d1; i2 = i1; d1 = d0; i1 = i0; d0 = dd; i0 = s; }
            else if (dd < d1) { d2 = d1; i2 = i1; d1 = dd; i1 = s; }
            else              { d2 = dd; i2 = s; }
        }
    }

    #pragma unroll
    for (int m = 1; m <= 8; m <<= 1) {
        float c0 = __shfl_xor(d0, m), c1 = __shfl_xor(d1, m), c2 = __shfl_xor(d2, m);
        int   j0 = __shfl_xor(i0, m), j1 = __shfl_xor(i1, m), j2 = __shfl_xor(i2, m);
        float cd[3] = {c0, c1, c2};
        int   cj[3] = {j0, j1, j2};
        #pragma unroll
        for (int k = 0; k < 3; ++k) {
            float d = cd[k]; int id = cj[k];
            bool l0 = (d < d0) || (d == d0 && id < i0);
            bool l1 = (d < d1) || (d == d1 && id < i1);
            bool l2 = (d < d2) || (d == d2 && id < i2);
            if (l0)      { d2 = d1; i2 = i1; d1 = d0; i1 = i0; d0 = d; i0 = id; }
            else if (l1) { d2 = d1; i2 = i1; d1 = d; i1 = id; }
            else if (l2) { d2 = d; i2 = id; }
        }
    }

    if (lp == 0) {
        float w0 = 1.f / fmaxf(d0, 1e-10f);
        float w1 = 1.f / fmaxf(d1, 1e-10f);
        float w2 = 1.f / fmaxf(d2, 1e-10f);
        float inv = 1.f / (w0 + w1 + w2);
        i0 = ((unsigned)i0 < S) ? i0 : 0;
        i1 = ((unsigned)i1 < S) ? i1 : 0;
        i2 = ((unsigned)i2 < S) ? i2 : 0;
        int base = (b * N + qi) * 3;
        wgt[base + 0] = w0 * inv; wgt[base + 1] = w1 * inv; wgt[base + 2] = w2 * inv;
        idxb[base + 0] = i0; idxb[base + 1] = i1; idxb[base + 2] = i2;
    }
}

// --------------------------------------------------------- transpose -----
// per-batch fp32 [C,L] -> bf16 [L,C]; 64x64 tiles, 256 threads.
__global__ __launch_bounds__(256) void transpose_k(
    const float* __restrict__ in, __hip_bfloat16* __restrict__ out,
    int L, int C)
{
    __shared__ ushort tl[64][66];
    const int b = blockIdx.z;
    const int l0 = blockIdx.x * 64, c0 = blockIdx.y * 64;
    const int t = threadIdx.x;
    const float* ip = in + (size_t)b * C * L;
    const int lr = t & 63, cb = t >> 6;
    #pragma unroll
    for (int i = 0; i < 16; ++i) {
        int c = cb + 4 * i;
        tl[lr][c] = f2u(ip[(size_t)(c0 + c) * L + l0 + lr]);
    }
    __syncthreads();
    ushort* op = (ushort*)out + (size_t)b * L * C;
    const int cp = t & 31, lrow = t >> 5;
    #pragma unroll
    for (int i = 0; i < 8; ++i) {
        int l = lrow + 8 * i;
        ushort2 v;
        v.x = tl[l][2 * cp];
        v.y = tl[l][2 * cp + 1];
        *(ushort2*)(op + (size_t)(l0 + l) * C + c0 + 2 * cp) = v;
    }
}

// ---------------------------------------------------------- GEMM common ---
// LDS X-tile: 32 rows x K, stored as 16B chunks with XOR swizzle:
//   chunk c of row r lives at element offset r*K + ((c ^ (r&7)) * 8)

// ------------------------------------------------ GEMM1 (fused interp) ----
// 256 thr = 4 waves; 32 rows/block; wave = (row-group rg = w>>1) x (o-half oh = w&1)
__global__ __launch_bounds__(256, 4) void gemm1_kernel(
    const __hip_bfloat16* __restrict__ W, const float* __restrict__ bias,
    const __hip_bfloat16* __restrict__ f2T, const __hip_bfloat16* __restrict__ f1T,
    const int* __restrict__ idxb, const float* __restrict__ wgt,
    __hip_bfloat16* __restrict__ y, float* __restrict__ sums)
{
    __shared__ __align__(16) ushort Xs[32 * 384];   // 24 KB
    __shared__ float statS[4][256];                 // 4 KB
    __shared__ float statQ[4][256];                 // 4 KB
    const int t = threadIdx.x;
    const int b = blockIdx.y;
    const int n0 = blockIdx.x * 32;

    // ---- stage interp (ch 0..255): 16B gathers, 2 rows per wave-instr ----
    {
        const int lp = t & 31, ro = t >> 5;           // ro 0..7; r&7 == ro
        #pragma unroll
        for (int it = 0; it < 4; ++it) {
            int r = ro + 8 * it;
            int base = (b * N + n0 + r) * 3;
            int s0 = idxb[base], s1 = idxb[base + 1], s2 = idxb[base + 2];
            s0 = ((unsigned)s0 < S) ? s0 : 0;
            s1 = ((unsigned)s1 < S) ? s1 : 0;
            s2 = ((unsigned)s2 < S) ? s2 : 0;
            float w0 = wgt[base], w1 = wgt[base + 1], w2 = wgt[base + 2];
            const ushort* r0p = (const ushort*)f2T + ((size_t)b * S + s0) * 256 + 8 * lp;
            const ushort* r1p = (const ushort*)f2T + ((size_t)b * S + s1) * 256 + 8 * lp;
            const ushort* r2p = (const ushort*)f2T + ((size_t)b * S + s2) * 256 + 8 * lp;
            union { short8 s; ushort u[8]; } a, c, d, o;
            a.s = *(const short8*)r0p; c.s = *(const short8*)r1p; d.s = *(const short8*)r2p;
            #pragma unroll
            for (int j = 0; j < 8; ++j)
                o.u[j] = f2u(w0 * u2f(a.u[j]) + w1 * u2f(c.u[j]) + w2 * u2f(d.u[j]));
            *(short8*)(Xs + r * 384 + ((lp ^ ro) * 8)) = o.s;
        }
    }
    // ---- stage f1 (ch 256..383) ----
    {
        const int lp = t & 15, ro = t >> 4;           // ro 0..15; r&7 == ro&7
        #pragma unroll
        for (int it = 0; it < 2; ++it) {
            int r = ro + 16 * it;
            short8 v = *(const short8*)((const ushort*)f1T + ((size_t)b * N + n0 + r) * 128 + 8 * lp);
            int c = 32 + lp;
            *(short8*)(Xs + r * 384 + ((c ^ (ro & 7)) * 8)) = v;
        }
    }
    __syncthreads();

    const int w = t >> 6, lane = t & 63;
    const int q = lane >> 4, r = lane & 15;
    const int rg = w >> 1, oh = w & 1;
    const int rowbase = rg * 16;

    v4f acc[8];
    #pragma unroll
    for (int mt = 0; mt < 8; ++mt) acc[mt] = (v4f){0.f, 0.f, 0.f, 0.f};

    const short* Wp = (const short*)W + (size_t)(oh * 128) * 384;
    const int rx = (rowbase + r) * 384, r7 = r & 7;

    #pragma unroll
    for (int kk = 0; kk < 12; ++kk) {
        short8 bf = *(const short8*)(Xs + rx + (((kk * 4 + q) ^ r7) * 8));
        #pragma unroll
        for (int mt = 0; mt < 8; ++mt) {
            short8 af = *(const short8*)(Wp + (size_t)(mt * 16 + r) * 384 + kk * 32 + q * 8);
            acc[mt] = __builtin_amdgcn_mfma_f32_16x16x32_bf16(af, bf, acc[mt], 0, 0, 0);
        }
    }

    // ---- epilogue: bias, store bf16 y, per-wave stats reduce ----
    {
        __hip_bfloat16* yr = y + ((size_t)b * N + n0 + rowbase + r) * 256;
        #pragma unroll
        for (int mt = 0; mt < 8; ++mt) {
            int o = oh * 128 + mt * 16 + q * 4;
            float4 bi = *(const float4*)(bias + o);
            float v0 = acc[mt][0] + bi.x, v1 = acc[mt][1] + bi.y;
            float v2 = acc[mt][2] + bi.z, v3 = acc[mt][3] + bi.w;
            ushort4 pk; pk.x = f2u(v0); pk.y = f2u(v1); pk.z = f2u(v2); pk.w = f2u(v3);
            *(ushort4*)(yr + o) = pk;
            float s0 = v0, s1 = v1, s2 = v2, s3 = v3;
            float q0 = v0 * v0, q1 = v1 * v1, q2 = v2 * v2, q3 = v3 * v3;
            #pragma unroll
            for (int m = 1; m <= 8; m <<= 1) {
                s0 += __shfl_xor(s0, m); s1 += __shfl_xor(s1, m);
                s2 += __shfl_xor(s2, m); s3 += __shfl_xor(s3, m);
                q0 += __shfl_xor(q0, m); q1 += __shfl_xor(q1, m);
                q2 += __shfl_xor(q2, m); q3 += __shfl_xor(q3, m);
            }
            if (r == 0) {
                statS[w][o + 0] = s0; statS[w][o + 1] = s1;
                statS[w][o + 2] = s2; statS[w][o + 3] = s3;
                statQ[w][o + 0] = q0; statQ[w][o + 1] = q1;
                statQ[w][o + 2] = q2; statQ[w][o + 3] = q3;
            }
        }
    }
    __syncthreads();
    {
        int c = t;
        int wA = (c < 128) ? 0 : 1, wB = wA + 2;
        atomicAdd(&sums[c],       statS[wA][c] + statS[wB][c]);
        atomicAdd(&sums[256 + c], statQ[wA][c] + statQ[wB][c]);
    }
}

// ------------------------ GEMM2 (BN1+ReLU on load, in-place, fused stats) --
__global__ __launch_bounds__(256, 4) void gemm2_kernel(
    const __hip_bfloat16* __restrict__ W, const float* __restrict__ bias,
    const float* __restrict__ sums1, const float* __restrict__ g1,
    const float* __restrict__ be1,
    __hip_bfloat16* __restrict__ y, float* __restrict__ sums)
{
    __shared__ __align__(16) ushort Xs[32 * 256];   // 16 KB
    __shared__ float statS[4][256];
    __shared__ float statQ[4][256];
    __shared__ float ssA[256], ssB[256];
    const int t = threadIdx.x;
    const int b = blockIdx.y;
    const int n0 = blockIdx.x * 32;

    // ---- preamble: finalize BN1 params from sums1 ----
    {
        float sv = sums1[t], qv = sums1[256 + t];
        float mean = sv * (1.f / 32768.f);
        float var = qv * (1.f / 32768.f) - mean * mean;
        float rstd = rsqrtf(var + 1e-5f);
        float sc = g1[t] * rstd;
        ssA[t] = sc;
        ssB[t] = be1[t] - mean * sc;
    }
    __syncthreads();

    // ---- stage y rows with BN+ReLU applied ----
    {
        const int lp = t & 31, ro = t >> 5;
        #pragma unroll
        for (int it = 0; it < 4; ++it) {
            int r = ro + 8 * it;
            union { short8 s; ushort u[8]; } v, o;
            v.s = *(const short8*)((const ushort*)y + ((size_t)b * N + n0 + r) * 256 + 8 * lp);
            #pragma unroll
            for (int j = 0; j < 8; ++j)
                o.u[j] = f2u(fmaxf(u2f(v.u[j]) * ssA[8 * lp + j] + ssB[8 * lp + j], 0.f));
            *(short8*)(Xs + r * 256 + ((lp ^ ro) * 8)) = o.s;
        }
    }
    __syncthreads();

    const int w = t >> 6, lane = t & 63;
    const int q = lane >> 4, r = lane & 15;
    const int rg = w >> 1, oh = w & 1;
    const int rowbase = rg * 16;

    v4f acc[8];
    #pragma unroll
    for (int mt = 0; mt < 8; ++mt) acc[mt] = (v4f){0.f, 0.f, 0.f, 0.f};

    const short* Wp = (const short*)W + (size_t)(oh * 128) * 256;
    const int rx = (rowbase + r) * 256, r7 = r & 7;

    #pragma unroll
    for (int kk = 0; kk < 8; ++kk) {
        short8 bf = *(const short8*)(Xs + rx + (((kk * 4 + q) ^ r7) * 8));
        #pragma unroll
        for (int mt = 0; mt < 8; ++mt) {
            short8 af = *(const short8*)(Wp + (size_t)(mt * 16 + r) * 256 + kk * 32 + q * 8);
            acc[mt] = __builtin_amdgcn_mfma_f32_16x16x32_bf16(af, bf, acc[mt], 0, 0, 0);
        }
    }

    {
        __hip_bfloat16* yr = y + ((size_t)b * N + n0 + rowbase + r) * 256;
        #pragma unroll
        for (int mt = 0; mt < 8; ++mt) {
            int o = oh * 128 + mt * 16 + q * 4;
            float4 bi = *(const float4*)(bias + o);
            float v0 = acc[mt][0] + bi.x, v1 = acc[mt][1] + bi.y;
            float v2 = acc[mt][2] + bi.z, v3 = acc[mt][3] + bi.w;
            ushort4 pk; pk.x = f2u(v0); pk.y = f2u(v1); pk.z = f2u(v2); pk.w = f2u(v3);
            *(ushort4*)(yr + o) = pk;
            float s0 = v0, s1 = v1, s2 = v2, s3 = v3;
            float q0 = v0 * v0, q1 = v1 * v1, q2 = v2 * v2, q3 = v3 * v3;
            #pragma unroll
            for (int m = 1; m <= 8; m <<= 1) {
                s0 += __shfl_xor(s0, m); s1 += __shfl_xor(s1, m);
                s2 += __shfl_xor(s2, m); s3 += __shfl_xor(s3, m);
                q0 += __shfl_xor(q0, m); q1 += __shfl_xor(q1, m);
                q2 += __shfl_xor(q2, m); q3 += __shfl_xor(q3, m);
            }
            if (r == 0) {
                statS[w][o + 0] = s0; statS[w][o + 1] = s1;
                statS[w][o + 2] = s2; statS[w][o + 3] = s3;
                statQ[w][o + 0] = q0; statQ[w][o + 1] = q1;
                statQ[w][o + 2] = q2; statQ[w][o + 3] = q3;
            }
        }
    }
    __syncthreads();
    {
        int c = t;
        int wA = (c < 128) ? 0 : 1, wB = wA + 2;
        atomicAdd(&sums[c],       statS[wA][c] + statS[wB][c]);
        atomicAdd(&sums[256 + c], statQ[wA][c] + statQ[wB][c]);
    }
}

// ------------- final: BN2+ReLU + transpose to [B,256,N] fp32 (64x64) ------
__global__ __launch_bounds__(256) void final_kernel(
    const __hip_bfloat16* __restrict__ Y, const float* __restrict__ sums2,
    const float* __restrict__ g2, const float* __restrict__ be2,
    float* __restrict__ out)
{
    __shared__ float tl[64][65];
    __shared__ float ssA[64], ssB[64];
    const int t = threadIdx.x;
    const int b = blockIdx.z;
    const int n0 = blockIdx.x * 64, c0 = blockIdx.y * 64;

    if (t < 64) {
        int c = c0 + t;
        float sv = sums2[c], qv = sums2[256 + c];
        float mean = sv * (1.f / 32768.f);
        float var = qv * (1.f / 32768.f) - mean * mean;
        float rstd = rsqrtf(var + 1e-5f);
        float sc = g2[c] * rstd;
        ssA[t] = sc;
        ssB[t] = be2[c] - mean * sc;
    }
    __syncthreads();

    const int nl = t >> 3, cho = 8 * (t & 7);
    #pragma unroll
    for (int it = 0; it < 2; ++it) {
        int n = nl + 32 * it;
        union { short8 s; ushort u[8]; } v;
        v.s = *(const short8*)((const ushort*)Y + ((size_t)b * N + n0 + n) * 256 + c0 + cho);
        #pragma unroll
        for (int j = 0; j < 8; ++j)
            tl[n][cho + j] = fmaxf(u2f(v.u[j]) * ssA[cho + j] + ssB[cho + j], 0.f);
    }
    __syncthreads();

    const int cl = t >> 4, n4 = (t & 15) * 4;
    #pragma unroll
    for (int it = 0; it < 4; ++it) {
        int c = cl + 16 * it;
        float4 v;
        v.x = tl[n4 + 0][c]; v.y = tl[n4 + 1][c];
        v.z = tl[n4 + 2][c]; v.w = tl[n4 + 3][c];
        *(float4*)(out + ((size_t)b * 256 + c0 + c) * N + n0 + n4) = v;
    }
}

// ------------------------------------------------------------ launch -----
extern "C" void kernel_launch(void* const* d_in, const int* in_sizes, int n_in,
                              void* d_out, int out_size, void* d_ws, size_t ws_size,
                              hipStream_t stream)
{
    (void)in_sizes; (void)n_in; (void)out_size;
    // ws layout (30 MB):
    //  [0,384K) idxb | [384K,768K) wgt | [768K,+4K) sums1(1024f incl sums2)
    //  [800K..992K) W1c | [992K..1.12M) W2c | [2M,6M) f2T | [6M,14M) f1T | [14M,30M) y
    if (ws_size < (30u << 20)) return;

    const float* pos1 = (const float*)d_in[0];
    const float* pos2 = (const float*)d_in[1];
    const float* f1   = (const float*)d_in[2];
    const float* f2   = (const float*)d_in[3];
    const float* W1   = (const float*)d_in[4];
    const float* b1   = (const float*)d_in[5];
    const float* g1   = (const float*)d_in[6];
    const float* be1  = (const float*)d_in[7];
    const float* W2   = (const float*)d_in[8];
    const float* b2   = (const float*)d_in[9];
    const float* g2   = (const float*)d_in[10];
    const float* be2  = (const float*)d_in[11];

    char* ws = (char*)d_ws;
    int*   idxb  = (int*)(ws + 0);
    float* wgt   = (float*)(ws + 393216);
    float* sums1 = (float*)(ws + 786432);
    float* sums2 = sums1 + 512;
    __hip_bfloat16* W1c = (__hip_bfloat16*)(ws + 819200);
    __hip_bfloat16* W2c = (__hip_bfloat16*)(ws + 1015808);
    __hip_bfloat16* f2T = (__hip_bfloat16*)(ws + (2u << 20));
    __hip_bfloat16* f1T = (__hip_bfloat16*)(ws + (6u << 20));
    __hip_bfloat16* y   = (__hip_bfloat16*)(ws + (14u << 20));

    prep_kernel<<<644, 256, 0, stream>>>(W1, W2, W1c, W2c, sums1);

    knn_kernel<<<dim3(N / 16, B), 256, 0, stream>>>(pos1, pos2, wgt, idxb);

    transpose_k<<<dim3(S / 64, 256 / 64, B), 256, 0, stream>>>(f2, f2T, S, 256);
    transpose_k<<<dim3(N / 64, 128 / 64, B), 256, 0, stream>>>(f1, f1T, N, 128);

    gemm1_kernel<<<dim3(N / 32, B), 256, 0, stream>>>(
        W1c, b1, f2T, f1T, idxb, wgt, y, sums1);
    gemm2_kernel<<<dim3(N / 32, B), 256, 0, stream>>>(
        W2c, b2, sums1, g1, be1, y, sums2);
    final_kernel<<<dim3(N / 64, 256 / 64, B), 256, 0, stream>>>(
        y, sums2, g2, be2, (float*)d_out);
}

// Round 6
// 214.235 us; speedup vs baseline: 1.4993x; 1.3559x over previous
//
#include <hip/hip_runtime.h>
#include <hip/hip_bf16.h>

constexpr int B = 4, N = 8192, S = 2048;

typedef __attribute__((ext_vector_type(8))) short short8;
typedef __attribute__((ext_vector_type(4))) float v4f;

__device__ inline float u2f(ushort u) {
    union { ushort u; __hip_bfloat16 h; } c; c.u = u; return __bfloat162float(c.h);
}
__device__ inline ushort f2u(float f) {
    union { ushort u; __hip_bfloat16 h; } c; c.h = __float2bfloat16(f); return c.u;
}
__device__ inline void async_lds16(const void* g, void* l) {
    __builtin_amdgcn_global_load_lds(
        (const __attribute__((address_space(1))) unsigned*)g,
        (__attribute__((address_space(3))) unsigned*)l, 16, 0, 0);
}
__device__ inline short8 ld8(const ushort* p) { return *(const short8*)p; }

// ----------------- prep: repack W to chunk-major [kk][q][o][8] bf16 -------
__global__ __launch_bounds__(256) void prep_kernel(
    const float* __restrict__ W1, const float* __restrict__ W2,
    __hip_bfloat16* __restrict__ W1r, __hip_bfloat16* __restrict__ W2r,
    float* __restrict__ zero_region)
{
    int i = blockIdx.x * 256 + threadIdx.x;
    if (i < 12288) {
        int kk = i >> 10, q = (i >> 8) & 3, o = i & 255;
        const float* src = W1 + o * 384 + kk * 32 + q * 8;
        float4 a = *(const float4*)src, b = *(const float4*)(src + 4);
        union { short8 s; ushort u[8]; } pk;
        pk.u[0] = f2u(a.x); pk.u[1] = f2u(a.y); pk.u[2] = f2u(a.z); pk.u[3] = f2u(a.w);
        pk.u[4] = f2u(b.x); pk.u[5] = f2u(b.y); pk.u[6] = f2u(b.z); pk.u[7] = f2u(b.w);
        *(short8*)((ushort*)W1r + i * 8) = pk.s;
    } else if (i < 20480) {
        int u = i - 12288;
        int kk = u >> 10, q = (u >> 8) & 3, o = u & 255;
        const float* src = W2 + o * 256 + kk * 32 + q * 8;
        float4 a = *(const float4*)src, b = *(const float4*)(src + 4);
        union { short8 s; ushort u[8]; } pk;
        pk.u[0] = f2u(a.x); pk.u[1] = f2u(a.y); pk.u[2] = f2u(a.z); pk.u[3] = f2u(a.w);
        pk.u[4] = f2u(b.x); pk.u[5] = f2u(b.y); pk.u[6] = f2u(b.z); pk.u[7] = f2u(b.w);
        *(short8*)((ushort*)W2r + u * 8) = pk.s;
    } else if (i < 21504) {
        zero_region[i - 20480] = 0.f;
    }
}

// ---------------------------------------------------------------- 3-NN ----
__global__ __launch_bounds__(256) void knn_kernel(
    const float* __restrict__ pos1, const float* __restrict__ pos2,
    float* __restrict__ wgt, int* __restrict__ idxb)
{
    __shared__ float4 p2s[S];
    const int b = blockIdx.y;
    for (int s = threadIdx.x; s < S; s += 256) {
        float x = pos2[(b * 3 + 0) * S + s];
        float y = pos2[(b * 3 + 1) * S + s];
        float z = pos2[(b * 3 + 2) * S + s];
        p2s[s] = make_float4(x, y, z, x * x + y * y + z * z);
    }
    __syncthreads();

    const int qi = blockIdx.x * 16 + (threadIdx.x >> 4);
    const int lp = threadIdx.x & 15;
    const float x1 = pos1[(b * 3 + 0) * N + qi];
    const float y1 = pos1[(b * 3 + 1) * N + qi];
    const float z1 = pos1[(b * 3 + 2) * N + qi];
    const float t1 = x1 * x1 + y1 * y1 + z1 * z1;

    float d0 = 3.4e38f, d1 = 3.4e38f, d2 = 3.4e38f;
    int i0 = 0x7fffffff, i1 = 0x7fffffff, i2 = 0x7fffffff;

    for (int t = 0; t < S / 16; ++t) {
        int s = 16 * t + lp;
        float4 p = p2s[s];
        float dot = x1 * p.x + y1 * p.y + z1 * p.z;
        float dd = (t1 - 2.0f * dot) + p.w;
        if (dd < d2) {
            if (dd < d0)      { d2 = d1; i2 = i1; d1 = d0; i1 = i0; d0 = dd; i0 = s; }
            else if (dd < d1) { d2 = d1; i2 = i1; d1 = dd; i1 = s; }
            else              { d2 = dd; i2 = s; }
        }
    }

    #pragma unroll
    for (int m = 1; m <= 8; m <<= 1) {
        float c0 = __shfl_xor(d0, m), c1 = __shfl_xor(d1, m), c2 = __shfl_xor(d2, m);
        int   j0 = __shfl_xor(i0, m), j1 = __shfl_xor(i1, m), j2 = __shfl_xor(i2, m);
        float cd[3] = {c0, c1, c2};
        int   cj[3] = {j0, j1, j2};
        #pragma unroll
        for (int k = 0; k < 3; ++k) {
            float d = cd[k]; int id = cj[k];
            bool l0 = (d < d0) || (d == d0 && id < i0);
            bool l1 = (d < d1) || (d == d1 && id < i1);
            bool l2 = (d < d2) || (d == d2 && id < i2);
            if (l0)      { d2 = d1; i2 = i1; d1 = d0; i1 = i0; d0 = d; i0 = id; }
            else if (l1) { d2 = d1; i2 = i1; d1 = d; i1 = id; }
            else if (l2) { d2 = d; i2 = id; }
        }
    }

    if (lp == 0) {
        float w0 = 1.f / fmaxf(d0, 1e-10f);
        float w1 = 1.f / fmaxf(d1, 1e-10f);
        float w2 = 1.f / fmaxf(d2, 1e-10f);
        float inv = 1.f / (w0 + w1 + w2);
        i0 = ((unsigned)i0 < S) ? i0 : 0;
        i1 = ((unsigned)i1 < S) ? i1 : 0;
        i2 = ((unsigned)i2 < S) ? i2 : 0;
        int base = (b * N + qi) * 3;
        wgt[base + 0] = w0 * inv; wgt[base + 1] = w1 * inv; wgt[base + 2] = w2 * inv;
        idxb[base + 0] = i0; idxb[base + 1] = i1; idxb[base + 2] = i2;
    }
}

// --------------------------------------------------------- transpose -----
__global__ __launch_bounds__(256) void transpose_k(
    const float* __restrict__ in, __hip_bfloat16* __restrict__ out,
    int L, int C)
{
    __shared__ ushort tl[64][66];
    const int b = blockIdx.z;
    const int l0 = blockIdx.x * 64, c0 = blockIdx.y * 64;
    const int t = threadIdx.x;
    const float* ip = in + (size_t)b * C * L;
    const int lr = t & 63, cb = t >> 6;
    #pragma unroll
    for (int i = 0; i < 16; ++i) {
        int c = cb + 4 * i;
        tl[lr][c] = f2u(ip[(size_t)(c0 + c) * L + l0 + lr]);
    }
    __syncthreads();
    ushort* op = (ushort*)out + (size_t)b * L * C;
    const int cp = t & 31, lrow = t >> 5;
    #pragma unroll
    for (int i = 0; i < 8; ++i) {
        int l = lrow + 8 * i;
        ushort2 v;
        v.x = tl[l][2 * cp];
        v.y = tl[l][2 * cp + 1];
        *(ushort2*)(op + (size_t)(l0 + l) * C + c0 + 2 * cp) = v;
    }
}

// ------------------------------------------------ GEMM1 (fused interp) ----
// 256 thr = 4 waves; 64 rows/block. Wave w computes o-quarter w*64..w*64+63
// for all 64 rows (mt=4 x nf=4 = 16 MFMA per chunk, 8 ds_reads, 0 global).
// W staged per-K-chunk via global_load_lds, double-buffered.
__global__ __launch_bounds__(256) void gemm1_kernel(
    const __hip_bfloat16* __restrict__ Wr, const float* __restrict__ bias,
    const __hip_bfloat16* __restrict__ f2T, const __hip_bfloat16* __restrict__ f1T,
    const int* __restrict__ idxb, const float* __restrict__ wgt,
    __hip_bfloat16* __restrict__ y, float* __restrict__ sums)
{
    __shared__ __align__(16) ushort Xs[64 * 384];      // 48 KB
    __shared__ __align__(16) ushort Wbuf[2 * 8192];    // 32 KB (2 x 16KB chunks)
    const int t = threadIdx.x;
    const int b = blockIdx.y;
    const int n0 = blockIdx.x * 64;
    const int w = t >> 6, lane = t & 63;
    const int q = lane >> 4, r = lane & 15, r7 = r & 7;

    // ---- prefetch W chunk 0 ----
    {
        const char* g0 = (const char*)Wr;
        #pragma unroll
        for (int jj = 0; jj < 4; ++jj)
            async_lds16(g0 + jj * 4096 + t * 16,
                        (char*)Wbuf + jj * 4096 + w * 1024);
    }

    // ---- stage interp (ch 0..255) ----
    {
        const int lp = t & 31, ro = t >> 5;
        #pragma unroll
        for (int it = 0; it < 8; ++it) {
            int rr = ro + 8 * it;
            int base = (b * N + n0 + rr) * 3;
            int s0 = idxb[base], s1 = idxb[base + 1], s2 = idxb[base + 2];
            s0 = ((unsigned)s0 < S) ? s0 : 0;
            s1 = ((unsigned)s1 < S) ? s1 : 0;
            s2 = ((unsigned)s2 < S) ? s2 : 0;
            float w0 = wgt[base], w1 = wgt[base + 1], w2 = wgt[base + 2];
            union { short8 s; ushort u[8]; } a, c, d, o;
            a.s = ld8((const ushort*)f2T + ((size_t)b * S + s0) * 256 + 8 * lp);
            c.s = ld8((const ushort*)f2T + ((size_t)b * S + s1) * 256 + 8 * lp);
            d.s = ld8((const ushort*)f2T + ((size_t)b * S + s2) * 256 + 8 * lp);
            #pragma unroll
            for (int j = 0; j < 8; ++j)
                o.u[j] = f2u(w0 * u2f(a.u[j]) + w1 * u2f(c.u[j]) + w2 * u2f(d.u[j]));
            *(short8*)(Xs + rr * 384 + ((lp ^ ro) * 8)) = o.s;
        }
    }
    // ---- stage f1 (ch 256..383) ----
    {
        const int lp = t & 15, ro = t >> 4;
        #pragma unroll
        for (int it = 0; it < 4; ++it) {
            int rr = ro + 16 * it;
            short8 v = ld8((const ushort*)f1T + ((size_t)b * N + n0 + rr) * 128 + 8 * lp);
            int c = 32 + lp;
            *(short8*)(Xs + rr * 384 + ((c ^ (rr & 7)) * 8)) = v;
        }
    }
    __syncthreads();   // drains W chunk 0 + X staging

    v4f acc[4][4];
    #pragma unroll
    for (int mt = 0; mt < 4; ++mt)
        #pragma unroll
        for (int nf = 0; nf < 4; ++nf) acc[mt][nf] = (v4f){0.f, 0.f, 0.f, 0.f};

    for (int kk = 0; kk < 12; ++kk) {
        if (kk < 11) {
            const char* g = (const char*)Wr + (kk + 1) * 16384;
            char* l = (char*)Wbuf + ((kk + 1) & 1) * 16384;
            #pragma unroll
            for (int jj = 0; jj < 4; ++jj)
                async_lds16(g + jj * 4096 + t * 16, l + jj * 4096 + w * 1024);
        }
        const ushort* Wb = Wbuf + (kk & 1) * 8192;
        short8 af[4], bf[4];
        #pragma unroll
        for (int mt = 0; mt < 4; ++mt)
            af[mt] = ld8(Wb + q * 2048 + (w * 64 + mt * 16 + r) * 8);
        #pragma unroll
        for (int nf = 0; nf < 4; ++nf)
            bf[nf] = ld8(Xs + (nf * 16 + r) * 384 + (((kk * 4 + q) ^ r7) * 8));
        #pragma unroll
        for (int mt = 0; mt < 4; ++mt)
            #pragma unroll
            for (int nf = 0; nf < 4; ++nf)
                acc[mt][nf] = __builtin_amdgcn_mfma_f32_16x16x32_bf16(
                    af[mt], bf[nf], acc[mt][nf], 0, 0, 0);
        __syncthreads();   // drains prefetch; protects Wbuf reuse
    }

    // ---- epilogue: bias, y store, block stats (statS/Q alias Xs) ----
    float* statS = (float*)Xs;
    float* statQ = statS + 256;
    #pragma unroll
    for (int mt = 0; mt < 4; ++mt) {
        int ob = w * 64 + mt * 16 + q * 4;
        float4 bi = *(const float4*)(bias + ob);
        float sj0 = 0, sj1 = 0, sj2 = 0, sj3 = 0;
        float qj0 = 0, qj1 = 0, qj2 = 0, qj3 = 0;
        #pragma unroll
        for (int nf = 0; nf < 4; ++nf) {
            int n = n0 + nf * 16 + r;
            float v0 = acc[mt][nf][0] + bi.x, v1 = acc[mt][nf][1] + bi.y;
            float v2 = acc[mt][nf][2] + bi.z, v3 = acc[mt][nf][3] + bi.w;
            ushort4 pk; pk.x = f2u(v0); pk.y = f2u(v1); pk.z = f2u(v2); pk.w = f2u(v3);
            *(ushort4*)((ushort*)y + ((size_t)b * N + n) * 256 + ob) = pk;
            sj0 += v0; sj1 += v1; sj2 += v2; sj3 += v3;
            qj0 += v0 * v0; qj1 += v1 * v1; qj2 += v2 * v2; qj3 += v3 * v3;
        }
        #pragma unroll
        for (int m = 1; m <= 8; m <<= 1) {
            sj0 += __shfl_xor(sj0, m); sj1 += __shfl_xor(sj1, m);
            sj2 += __shfl_xor(sj2, m); sj3 += __shfl_xor(sj3, m);
            qj0 += __shfl_xor(qj0, m); qj1 += __shfl_xor(qj1, m);
            qj2 += __shfl_xor(qj2, m); qj3 += __shfl_xor(qj3, m);
        }
        if (r == 0) {
            statS[ob + 0] = sj0; statS[ob + 1] = sj1;
            statS[ob + 2] = sj2; statS[ob + 3] = sj3;
            statQ[ob + 0] = qj0; statQ[ob + 1] = qj1;
            statQ[ob + 2] = qj2; statQ[ob + 3] = qj3;
        }
    }
    __syncthreads();
    atomicAdd(&sums[t], statS[t]);
    atomicAdd(&sums[256 + t], statQ[t]);
}

// ------------------------ GEMM2 (BN1+ReLU on load, in-place, fused stats) --
__global__ __launch_bounds__(256) void gemm2_kernel(
    const __hip_bfloat16* __restrict__ Wr, const float* __restrict__ bias,
    const float* __restrict__ sums1, const float* __restrict__ g1,
    const float* __restrict__ be1,
    __hip_bfloat16* __restrict__ y, float* __restrict__ sums)
{
    __shared__ __align__(16) ushort Xs[64 * 256];      // 32 KB
    __shared__ __align__(16) ushort Wbuf[2 * 8192];    // 32 KB
    __shared__ float ssA[256], ssB[256];
    const int t = threadIdx.x;
    const int b = blockIdx.y;
    const int n0 = blockIdx.x * 64;
    const int w = t >> 6, lane = t & 63;
    const int q = lane >> 4, r = lane & 15, r7 = r & 7;

    // ---- prefetch W chunk 0 ----
    {
        const char* g0 = (const char*)Wr;
        #pragma unroll
        for (int jj = 0; jj < 4; ++jj)
            async_lds16(g0 + jj * 4096 + t * 16,
                        (char*)Wbuf + jj * 4096 + w * 1024);
    }

    // ---- BN1 finalize ----
    {
        float sv = sums1[t], qv = sums1[256 + t];
        float mean = sv * (1.f / 32768.f);
        float var = qv * (1.f / 32768.f) - mean * mean;
        float rstd = rsqrtf(var + 1e-5f);
        float sc = g1[t] * rstd;
        ssA[t] = sc;
        ssB[t] = be1[t] - mean * sc;
    }
    __syncthreads();

    // ---- stage y rows with BN+ReLU ----
    {
        const int lp = t & 31, ro = t >> 5;
        #pragma unroll
        for (int it = 0; it < 8; ++it) {
            int rr = ro + 8 * it;
            union { short8 s; ushort u[8]; } v, o;
            v.s = ld8((const ushort*)y + ((size_t)b * N + n0 + rr) * 256 + 8 * lp);
            #pragma unroll
            for (int j = 0; j < 8; ++j)
                o.u[j] = f2u(fmaxf(u2f(v.u[j]) * ssA[8 * lp + j] + ssB[8 * lp + j], 0.f));
            *(short8*)(Xs + rr * 256 + ((lp ^ ro) * 8)) = o.s;
        }
    }
    __syncthreads();

    v4f acc[4][4];
    #pragma unroll
    for (int mt = 0; mt < 4; ++mt)
        #pragma unroll
        for (int nf = 0; nf < 4; ++nf) acc[mt][nf] = (v4f){0.f, 0.f, 0.f, 0.f};

    for (int kk = 0; kk < 8; ++kk) {
        if (kk < 7) {
            const char* g = (const char*)Wr + (kk + 1) * 16384;
            char* l = (char*)Wbuf + ((kk + 1) & 1) * 16384;
            #pragma unroll
            for (int jj = 0; jj < 4; ++jj)
                async_lds16(g + jj * 4096 + t * 16, l + jj * 4096 + w * 1024);
        }
        const ushort* Wb = Wbuf + (kk & 1) * 8192;
        short8 af[4], bf[4];
        #pragma unroll
        for (int mt = 0; mt < 4; ++mt)
            af[mt] = ld8(Wb + q * 2048 + (w * 64 + mt * 16 + r) * 8);
        #pragma unroll
        for (int nf = 0; nf < 4; ++nf)
            bf[nf] = ld8(Xs + (nf * 16 + r) * 256 + (((kk * 4 + q) ^ r7) * 8));
        #pragma unroll
        for (int mt = 0; mt < 4; ++mt)
            #pragma unroll
            for (int nf = 0; nf < 4; ++nf)
                acc[mt][nf] = __builtin_amdgcn_mfma_f32_16x16x32_bf16(
                    af[mt], bf[nf], acc[mt][nf], 0, 0, 0);
        __syncthreads();
    }

    float* statS = (float*)Xs;
    float* statQ = statS + 256;
    #pragma unroll
    for (int mt = 0; mt < 4; ++mt) {
        int ob = w * 64 + mt * 16 + q * 4;
        float4 bi = *(const float4*)(bias + ob);
        float sj0 = 0, sj1 = 0, sj2 = 0, sj3 = 0;
        float qj0 = 0, qj1 = 0, qj2 = 0, qj3 = 0;
        #pragma unroll
        for (int nf = 0; nf < 4; ++nf) {
            int n = n0 + nf * 16 + r;
            float v0 = acc[mt][nf][0] + bi.x, v1 = acc[mt][nf][1] + bi.y;
            float v2 = acc[mt][nf][2] + bi.z, v3 = acc[mt][nf][3] + bi.w;
            ushort4 pk; pk.x = f2u(v0); pk.y = f2u(v1); pk.z = f2u(v2); pk.w = f2u(v3);
            *(ushort4*)((ushort*)y + ((size_t)b * N + n) * 256 + ob) = pk;
            sj0 += v0; sj1 += v1; sj2 += v2; sj3 += v3;
            qj0 += v0 * v0; qj1 += v1 * v1; qj2 += v2 * v2; qj3 += v3 * v3;
        }
        #pragma unroll
        for (int m = 1; m <= 8; m <<= 1) {
            sj0 += __shfl_xor(sj0, m); sj1 += __shfl_xor(sj1, m);
            sj2 += __shfl_xor(sj2, m); sj3 += __shfl_xor(sj3, m);
            qj0 += __shfl_xor(qj0, m); qj1 += __shfl_xor(qj1, m);
            qj2 += __shfl_xor(qj2, m); qj3 += __shfl_xor(qj3, m);
        }
        if (r == 0) {
            statS[ob + 0] = sj0; statS[ob + 1] = sj1;
            statS[ob + 2] = sj2; statS[ob + 3] = sj3;
            statQ[ob + 0] = qj0; statQ[ob + 1] = qj1;
            statQ[ob + 2] = qj2; statQ[ob + 3] = qj3;
        }
    }
    __syncthreads();
    atomicAdd(&sums[t], statS[t]);
    atomicAdd(&sums[256 + t], statQ[t]);
}

// ------------- final: BN2+ReLU + transpose to [B,256,N] fp32 (64x64) ------
__global__ __launch_bounds__(256) void final_kernel(
    const __hip_bfloat16* __restrict__ Y, const float* __restrict__ sums2,
    const float* __restrict__ g2, const float* __restrict__ be2,
    float* __restrict__ out)
{
    __shared__ float tl[64][65];
    __shared__ float ssA[64], ssB[64];
    const int t = threadIdx.x;
    const int b = blockIdx.z;
    const int n0 = blockIdx.x * 64, c0 = blockIdx.y * 64;

    if (t < 64) {
        int c = c0 + t;
        float sv = sums2[c], qv = sums2[256 + c];
        float mean = sv * (1.f / 32768.f);
        float var = qv * (1.f / 32768.f) - mean * mean;
        float rstd = rsqrtf(var + 1e-5f);
        float sc = g2[c] * rstd;
        ssA[t] = sc;
        ssB[t] = be2[c] - mean * sc;
    }
    __syncthreads();

    const int nl = t >> 3, cho = 8 * (t & 7);
    #pragma unroll
    for (int it = 0; it < 2; ++it) {
        int n = nl + 32 * it;
        union { short8 s; ushort u[8]; } v;
        v.s = ld8((const ushort*)Y + ((size_t)b * N + n0 + n) * 256 + c0 + cho);
        #pragma unroll
        for (int j = 0; j < 8; ++j)
            tl[n][cho + j] = fmaxf(u2f(v.u[j]) * ssA[cho + j] + ssB[cho + j], 0.f);
    }
    __syncthreads();

    const int cl = t >> 4, n4 = (t & 15) * 4;
    #pragma unroll
    for (int it = 0; it < 4; ++it) {
        int c = cl + 16 * it;
        float4 v;
        v.x = tl[n4 + 0][c]; v.y = tl[n4 + 1][c];
        v.z = tl[n4 + 2][c]; v.w = tl[n4 + 3][c];
        *(float4*)(out + ((size_t)b * 256 + c0 + c) * N + n0 + n4) = v;
    }
}

// ------------------------------------------------------------ launch -----
extern "C" void kernel_launch(void* const* d_in, const int* in_sizes, int n_in,
                              void* d_out, int out_size, void* d_ws, size_t ws_size,
                              hipStream_t stream)
{
    (void)in_sizes; (void)n_in; (void)out_size;
    // ws layout (30 MB):
    //  [0,384K) idxb | [384K,768K) wgt | [768K,+4K) sums1+sums2 (1024 floats)
    //  [800K,+192K) W1r | [992K,+128K) W2r | [2M,6M) f2T | [6M,14M) f1T | [14M,30M) y
    if (ws_size < (30u << 20)) return;

    const float* pos1 = (const float*)d_in[0];
    const float* pos2 = (const float*)d_in[1];
    const float* f1   = (const float*)d_in[2];
    const float* f2   = (const float*)d_in[3];
    const float* W1   = (const float*)d_in[4];
    const float* b1   = (const float*)d_in[5];
    const float* g1   = (const float*)d_in[6];
    const float* be1  = (const float*)d_in[7];
    const float* W2   = (const float*)d_in[8];
    const float* b2   = (const float*)d_in[9];
    const float* g2   = (const float*)d_in[10];
    const float* be2  = (const float*)d_in[11];

    char* ws = (char*)d_ws;
    int*   idxb  = (int*)(ws + 0);
    float* wgt   = (float*)(ws + 393216);
    float* sums1 = (float*)(ws + 786432);
    float* sums2 = sums1 + 512;
    __hip_bfloat16* W1r = (__hip_bfloat16*)(ws + 819200);
    __hip_bfloat16* W2r = (__hip_bfloat16*)(ws + 1015808);
    __hip_bfloat16* f2T = (__hip_bfloat16*)(ws + (2u << 20));
    __hip_bfloat16* f1T = (__hip_bfloat16*)(ws + (6u << 20));
    __hip_bfloat16* y   = (__hip_bfloat16*)(ws + (14u << 20));

    prep_kernel<<<84, 256, 0, stream>>>(W1, W2, W1r, W2r, sums1);

    knn_kernel<<<dim3(N / 16, B), 256, 0, stream>>>(pos1, pos2, wgt, idxb);

    transpose_k<<<dim3(S / 64, 256 / 64, B), 256, 0, stream>>>(f2, f2T, S, 256);
    transpose_k<<<dim3(N / 64, 128 / 64, B), 256, 0, stream>>>(f1, f1T, N, 128);

    gemm1_kernel<<<dim3(N / 64, B), 256, 0, stream>>>(
        W1r, b1, f2T, f1T, idxb, wgt, y, sums1);
    gemm2_kernel<<<dim3(N / 64, B), 256, 0, stream>>>(
        W2r, b2, sums1, g1, be1, y, sums2);
    final_kernel<<<dim3(N / 64, 256 / 64, B), 256, 0, stream>>>(
        y, sums2, g2, be2, (float*)d_out);
}